// Round 1
// baseline (7561.726 us; speedup 1.0000x reference)
//
#include <hip/hip_runtime.h>
#include <hip/hip_bf16.h>
#include <math.h>

typedef __bf16 bf16_t;
typedef __bf16 bf16x8 __attribute__((ext_vector_type(8)));
typedef float  f32x4 __attribute__((ext_vector_type(4)));
typedef float  f4    __attribute__((ext_vector_type(4)));

#define HS  512
#define BB  128
#define TT  40
#define VV  10000
#define VGGN 4096

// ============================================================================
// MFMA GEMM: C[M,N] = A[M,512] @ Bt[N,512]^T (+bias), fp32 out.
// A,Bt row-major bf16, K fixed = 512. 128x128 block tile, 4 waves of 64x64.
// Fragment layout (m91-verified): A/B lane holds row/col = lane&15,
// k = (lane>>4)*8 .. +7 (contiguous 8 bf16 = 16B load).
// C/D: row = (lane>>4)*4 + reg, col = lane&15.
// permute_tb: A-row m = t*128+b  ->  out row b*40+t (logits [B,T,V] layout).
// ============================================================================
__global__ __launch_bounds__(256) void gemm_bt(
    const bf16_t* __restrict__ A, const bf16_t* __restrict__ Bt,
    const float* __restrict__ bias, float* __restrict__ C,
    int Nvalid, int ldc, int permute_tb)
{
  const int bm = blockIdx.x * 128, bn = blockIdx.y * 128;
  const int tid = threadIdx.x;
  const int wave = tid >> 6, lane = tid & 63;
  const int wm = (wave >> 1) * 64, wn = (wave & 1) * 64;
  const int l15 = lane & 15, kg = lane >> 4;
  const bf16_t* Ap = A + (size_t)(bm + wm + l15) * 512 + kg * 8;
  const bf16_t* Bp = Bt + (size_t)(bn + wn + l15) * 512 + kg * 8;
  f32x4 acc[4][4];
#pragma unroll
  for (int i = 0; i < 4; ++i)
#pragma unroll
    for (int j = 0; j < 4; ++j)
#pragma unroll
      for (int e = 0; e < 4; ++e) acc[i][j][e] = 0.f;

  for (int kk = 0; kk < 512; kk += 32) {
    bf16x8 a[4], b[4];
#pragma unroll
    for (int i = 0; i < 4; ++i) a[i] = *(const bf16x8*)(Ap + (size_t)i * 16 * 512 + kk);
#pragma unroll
    for (int j = 0; j < 4; ++j) b[j] = *(const bf16x8*)(Bp + (size_t)j * 16 * 512 + kk);
#pragma unroll
    for (int i = 0; i < 4; ++i)
#pragma unroll
      for (int j = 0; j < 4; ++j)
        acc[i][j] = __builtin_amdgcn_mfma_f32_16x16x32_bf16(a[i], b[j], acc[i][j], 0, 0, 0);
  }

#pragma unroll
  for (int fm = 0; fm < 4; ++fm) {
#pragma unroll
    for (int fn = 0; fn < 4; ++fn) {
      int n = bn + wn + fn * 16 + l15;
      if (n >= Nvalid) continue;
      float bv = bias ? bias[n] : 0.f;
#pragma unroll
      for (int e = 0; e < 4; ++e) {
        int m = bm + wm + fm * 16 + kg * 4 + e;
        int orow = permute_tb ? ((m & 127) * TT + (m >> 7)) : m;
        C[(size_t)orow * ldc + n] = acc[fm][fn][e] + bv;
      }
    }
  }
}

// ============================================================================
// GRU r,u gates for one (layer, step): pre = hb@Btru^T + xg; u=sigmoid stored
// fp32; r=sigmoid, rh = bf16(r * h_fp32). Grid: 8 blocks (N'=1024), M=128.
// ============================================================================
__global__ __launch_bounds__(256) void gru_ru(
    const bf16_t* __restrict__ hb, const float* __restrict__ hs,
    const bf16_t* __restrict__ Btru, const float* __restrict__ xg_t,
    float* __restrict__ ubuf, bf16_t* __restrict__ rh)
{
  const int bn = blockIdx.x * 128;
  const int tid = threadIdx.x;
  const int wave = tid >> 6, lane = tid & 63;
  const int wm = (wave >> 1) * 64, wn = (wave & 1) * 64;
  const int l15 = lane & 15, kg = lane >> 4;
  const bf16_t* Ap = hb + (size_t)(wm + l15) * 512 + kg * 8;
  const bf16_t* Bp = Btru + (size_t)(bn + wn + l15) * 512 + kg * 8;
  f32x4 acc[4][4];
#pragma unroll
  for (int i = 0; i < 4; ++i)
#pragma unroll
    for (int j = 0; j < 4; ++j)
#pragma unroll
      for (int e = 0; e < 4; ++e) acc[i][j][e] = 0.f;

  for (int kk = 0; kk < 512; kk += 32) {
    bf16x8 a[4], b[4];
#pragma unroll
    for (int i = 0; i < 4; ++i) a[i] = *(const bf16x8*)(Ap + (size_t)i * 16 * 512 + kk);
#pragma unroll
    for (int j = 0; j < 4; ++j) b[j] = *(const bf16x8*)(Bp + (size_t)j * 16 * 512 + kk);
#pragma unroll
    for (int i = 0; i < 4; ++i)
#pragma unroll
      for (int j = 0; j < 4; ++j)
        acc[i][j] = __builtin_amdgcn_mfma_f32_16x16x32_bf16(a[i], b[j], acc[i][j], 0, 0, 0);
  }

#pragma unroll
  for (int fm = 0; fm < 4; ++fm) {
#pragma unroll
    for (int fn = 0; fn < 4; ++fn) {
      int np = bn + wn + fn * 16 + l15;   // 0..1023: <512 -> u, >=512 -> r
#pragma unroll
      for (int e = 0; e < 4; ++e) {
        int m = wm + fm * 16 + kg * 4 + e;
        float pre = acc[fm][fn][e] + xg_t[(size_t)m * 1536 + np];
        float s = 1.f / (1.f + expf(-pre));
        if (np < 512) {
          ubuf[m * 512 + np] = s;
        } else {
          int n = np - 512;
          rh[m * 512 + n] = (bf16_t)(s * hs[m * 512 + n]);
        }
      }
    }
  }
}

// ============================================================================
// GRU candidate + state update for one (layer, step):
// c = tanh(rh@Btc^T + xg_c); h_new = u*h + (1-u)*c. Grid: 4 blocks (N=512).
// ============================================================================
__global__ __launch_bounds__(256) void gru_c(
    const bf16_t* __restrict__ rh, const bf16_t* __restrict__ Btc,
    const float* __restrict__ xg_t, const float* __restrict__ ubuf,
    const float* __restrict__ hs_prev, float* __restrict__ hs_out,
    bf16_t* __restrict__ hb_out)
{
  const int bn = blockIdx.x * 128;
  const int tid = threadIdx.x;
  const int wave = tid >> 6, lane = tid & 63;
  const int wm = (wave >> 1) * 64, wn = (wave & 1) * 64;
  const int l15 = lane & 15, kg = lane >> 4;
  const bf16_t* Ap = rh + (size_t)(wm + l15) * 512 + kg * 8;
  const bf16_t* Bp = Btc + (size_t)(bn + wn + l15) * 512 + kg * 8;
  f32x4 acc[4][4];
#pragma unroll
  for (int i = 0; i < 4; ++i)
#pragma unroll
    for (int j = 0; j < 4; ++j)
#pragma unroll
      for (int e = 0; e < 4; ++e) acc[i][j][e] = 0.f;

  for (int kk = 0; kk < 512; kk += 32) {
    bf16x8 a[4], b[4];
#pragma unroll
    for (int i = 0; i < 4; ++i) a[i] = *(const bf16x8*)(Ap + (size_t)i * 16 * 512 + kk);
#pragma unroll
    for (int j = 0; j < 4; ++j) b[j] = *(const bf16x8*)(Bp + (size_t)j * 16 * 512 + kk);
#pragma unroll
    for (int i = 0; i < 4; ++i)
#pragma unroll
      for (int j = 0; j < 4; ++j)
        acc[i][j] = __builtin_amdgcn_mfma_f32_16x16x32_bf16(a[i], b[j], acc[i][j], 0, 0, 0);
  }

#pragma unroll
  for (int fm = 0; fm < 4; ++fm) {
#pragma unroll
    for (int fn = 0; fn < 4; ++fn) {
      int n = bn + wn + fn * 16 + l15;   // 0..511
#pragma unroll
      for (int e = 0; e < 4; ++e) {
        int m = wm + fm * 16 + kg * 4 + e;
        float c = tanhf(acc[fm][fn][e] + xg_t[(size_t)m * 1536 + 1024 + n]);
        float u = ubuf[m * 512 + n];
        float h = hs_prev[m * 512 + n];
        float hn = u * h + (1.f - u) * c;
        hs_out[m * 512 + n] = hn;
        hb_out[m * 512 + n] = (bf16_t)hn;
      }
    }
  }
}

// ============================================================================
// h0 = tanh(vgg @ W_in + b_in): fp32 tiled GEMM, M=128 N=512 K=4096.
// BM=BN=64, BK=16, 256 threads, 4x4 outputs/thread. Writes fp32 + bf16 state
// for both layers (shared initial hidden state).
// ============================================================================
__global__ __launch_bounds__(256) void h0_init(
    const float* __restrict__ vgg, const float* __restrict__ Win,
    const float* __restrict__ bin,
    float* __restrict__ hs0_0, float* __restrict__ hs1_0,
    bf16_t* __restrict__ hb0_0, bf16_t* __restrict__ hb1_0)
{
  __shared__ float As[16 * 68];
  __shared__ float Bs[16 * 68];
  const int bm = blockIdx.x * 64, bn = blockIdx.y * 64;
  const int tid = threadIdx.x;
  const int tx = tid & 15, ty = tid >> 4;
  float acc[4][4] = {};
  const int ka = tid & 15, ma = tid >> 4;
  const int nb = tid & 63, kb = tid >> 6;

  for (int kk = 0; kk < VGGN; kk += 16) {
#pragma unroll
    for (int r = 0; r < 4; ++r)
      As[ka * 68 + ma + r * 16] = vgg[(size_t)(bm + ma + r * 16) * VGGN + kk + ka];
#pragma unroll
    for (int r = 0; r < 4; ++r)
      Bs[(kb + r * 4) * 68 + nb] = Win[(size_t)(kk + kb + r * 4) * 512 + bn + nb];
    __syncthreads();
#pragma unroll
    for (int k = 0; k < 16; ++k) {
      f4 av = *(const f4*)&As[k * 68 + ty * 4];
      f4 bv = *(const f4*)&Bs[k * 68 + tx * 4];
#pragma unroll
      for (int i = 0; i < 4; ++i)
#pragma unroll
        for (int j = 0; j < 4; ++j)
          acc[i][j] += av[i] * bv[j];
    }
    __syncthreads();
  }
#pragma unroll
  for (int i = 0; i < 4; ++i) {
#pragma unroll
    for (int j = 0; j < 4; ++j) {
      int m = bm + ty * 4 + i, n = bn + tx * 4 + j;
      float v = tanhf(acc[i][j] + bin[n]);
      hs0_0[m * 512 + n] = v;
      hs1_0[m * 512 + n] = v;
      hb0_0[m * 512 + n] = (bf16_t)v;
      hb1_0[m * 512 + n] = (bf16_t)v;
    }
  }
}

// Embedding gather -> bf16 A matrix, row m = t*128+b.
__global__ void gather_emb(const int* __restrict__ tok, const float* __restrict__ emb,
                           bf16_t* __restrict__ A)
{
  int m = blockIdx.x;
  int t = m >> 7, b = m & 127;
  int tk = tok[b * TT + t];
  const float* src = emb + (size_t)tk * 512;
  int i = threadIdx.x;  // 128 threads, 4 elems each
  f4 v = *(const f4*)(src + i * 4);
  bf16_t* dst = A + (size_t)m * 512 + i * 4;
  dst[0] = (bf16_t)v[0]; dst[1] = (bf16_t)v[1];
  dst[2] = (bf16_t)v[2]; dst[3] = (bf16_t)v[3];
}

// 12 batched 512x512 transposes (f32 -> bf16): dst[n][k] = src[k][n].
struct TJobs { const float* src[12]; bf16_t* dst[12]; };
__global__ void transpose12(TJobs jobs)
{
  __shared__ float tile[32][33];
  const float* src = jobs.src[blockIdx.z];
  bf16_t* dst = jobs.dst[blockIdx.z];
  int k0 = blockIdx.x * 32, n0 = blockIdx.y * 32;
  int tx = threadIdx.x, ty = threadIdx.y;
#pragma unroll
  for (int r = 0; r < 4; ++r)
    tile[ty + 8 * r][tx] = src[(size_t)(k0 + ty + 8 * r) * 512 + n0 + tx];
  __syncthreads();
#pragma unroll
  for (int r = 0; r < 4; ++r)
    dst[(size_t)(n0 + ty + 8 * r) * 512 + k0 + tx] = (bf16_t)tile[tx][ty + 8 * r];
}

// W_out [512,10000] -> Wto [10112,512] bf16, zero-padded rows >= 10000.
__global__ void transpose_wout(const float* __restrict__ W, bf16_t* __restrict__ dst)
{
  __shared__ float tile[32][33];
  int k0 = blockIdx.x * 32, n0 = blockIdx.y * 32;
  int tx = threadIdx.x, ty = threadIdx.y;
#pragma unroll
  for (int r = 0; r < 4; ++r) {
    int n = n0 + tx;
    tile[ty + 8 * r][tx] = (n < VV) ? W[(size_t)(k0 + ty + 8 * r) * VV + n] : 0.f;
  }
  __syncthreads();
#pragma unroll
  for (int r = 0; r < 4; ++r)
    dst[(size_t)(n0 + ty + 8 * r) * 512 + k0 + tx] = (bf16_t)tile[tx][ty + 8 * r];
}

// xbias[j][1536] = concat(b_u[j], b_r[j], b_c[j])
__global__ void build_xbias(const float* __restrict__ bu, const float* __restrict__ br,
                            const float* __restrict__ bc, float* __restrict__ xb)
{
  int i = blockIdx.x * 256 + threadIdx.x;
  if (i < 2 * 1536) {
    int j = i / 1536, q = i % 1536;
    int g = q >> 9, n = q & 511;
    const float* src = (g == 0) ? bu : (g == 1) ? br : bc;
    xb[i] = src[j * 512 + n];
  }
}

__global__ void write_hfinal(const float* __restrict__ hs0_last,
                             const float* __restrict__ hs1_last,
                             float* __restrict__ out)
{
  int i = blockIdx.x * 256 + threadIdx.x;  // 65536 per layer
  out[i] = hs0_last[i];
  out[65536 + i] = hs1_last[i];
}

// ============================================================================
extern "C" void kernel_launch(void* const* d_in, const int* in_sizes, int n_in,
                              void* d_out, int out_size, void* d_ws, size_t ws_size,
                              hipStream_t stream)
{
  const int*   tok = (const int*)  d_in[0];
  const float* vgg = (const float*)d_in[1];
  const float* emb = (const float*)d_in[2];
  const float* Win = (const float*)d_in[3];
  const float* bin = (const float*)d_in[4];
  const float* Wu  = (const float*)d_in[5];
  const float* bu  = (const float*)d_in[6];
  const float* Wr  = (const float*)d_in[7];
  const float* br  = (const float*)d_in[8];
  const float* Wc  = (const float*)d_in[9];
  const float* bc  = (const float*)d_in[10];
  const float* Wo  = (const float*)d_in[11];
  const float* bo  = (const float*)d_in[12];
  float* out = (float*)d_out;

  size_t off = 0;
  auto alloc = [&](size_t bytes) -> void* {
    void* p = (char*)d_ws + off;
    off += (bytes + 255) & ~(size_t)255;
    return p;
  };
  const size_t SLOT = (size_t)BB * HS;  // 65536
  float*  hs0  = (float*) alloc(41 * SLOT * 4);
  float*  hs1  = (float*) alloc(41 * SLOT * 4);
  bf16_t* hb0  = (bf16_t*)alloc(41 * SLOT * 2);
  bf16_t* hb1  = (bf16_t*)alloc(41 * SLOT * 2);
  bf16_t* Aemb = (bf16_t*)alloc((size_t)TT * BB * 512 * 2);
  float*  xg   = (float*) alloc((size_t)TT * BB * 1536 * 4);
  bf16_t* Btx0 = (bf16_t*)alloc((size_t)1536 * 512 * 2);
  bf16_t* Btx1 = (bf16_t*)alloc((size_t)1536 * 512 * 2);
  bf16_t* Btru0= (bf16_t*)alloc((size_t)1024 * 512 * 2);
  bf16_t* Btru1= (bf16_t*)alloc((size_t)1024 * 512 * 2);
  bf16_t* Btc0 = (bf16_t*)alloc((size_t)512 * 512 * 2);
  bf16_t* Btc1 = (bf16_t*)alloc((size_t)512 * 512 * 2);
  bf16_t* Wto  = (bf16_t*)alloc((size_t)10112 * 512 * 2);
  float*  xbias= (float*) alloc(2 * 1536 * 4);
  float*  ubuf = (float*) alloc(SLOT * 4);
  bf16_t* rh   = (bf16_t*)alloc(SLOT * 2);
  if (off > ws_size) return;  // workspace too small: bail (will fail validation)

  const float* Wg[3] = {Wu, Wr, Wc};

  // ---- prep: weight transposes ----
  TJobs tj;
  int idx = 0;
  for (int j = 0; j < 2; ++j)          // x-parts (rows 0..511) of u,r,c
    for (int g = 0; g < 3; ++g) {
      tj.src[idx] = Wg[g] + (size_t)j * 1024 * 512;
      tj.dst[idx] = (j ? Btx1 : Btx0) + (size_t)g * 512 * 512;
      ++idx;
    }
  for (int j = 0; j < 2; ++j)          // h-parts (rows 512..1023) of u,r
    for (int g = 0; g < 2; ++g) {
      tj.src[idx] = Wg[g] + (size_t)j * 1024 * 512 + 512 * 512;
      tj.dst[idx] = (j ? Btru1 : Btru0) + (size_t)g * 512 * 512;
      ++idx;
    }
  for (int j = 0; j < 2; ++j) {        // h-part of c
    tj.src[idx] = Wc + (size_t)j * 1024 * 512 + 512 * 512;
    tj.dst[idx] = j ? Btc1 : Btc0;
    ++idx;
  }
  transpose12<<<dim3(16, 16, 12), dim3(32, 8), 0, stream>>>(tj);
  transpose_wout<<<dim3(16, 316), dim3(32, 8), 0, stream>>>(Wo, Wto);
  build_xbias<<<12, 256, 0, stream>>>(bu, br, bc, xbias);
  gather_emb<<<TT * BB, 128, 0, stream>>>(tok, emb, Aemb);
  h0_init<<<dim3(2, 8), 256, 0, stream>>>(vgg, Win, bin,
                                          hs0, hs1, hb0, hb1);

  // ---- layer 0 x-gates (batched) ----
  gemm_bt<<<dim3(40, 12), 256, 0, stream>>>(Aemb, Btx0, xbias, xg, 1536, 1536, 0);

  // ---- layer 0 recurrence ----
  for (int t = 0; t < TT; ++t) {
    const float* xg_t = xg + (size_t)t * BB * 1536;
    gru_ru<<<8, 256, 0, stream>>>(hb0 + t * SLOT, hs0 + t * SLOT, Btru0, xg_t, ubuf, rh);
    gru_c<<<4, 256, 0, stream>>>(rh, Btc0, xg_t, ubuf,
                                 hs0 + t * SLOT, hs0 + (t + 1) * SLOT, hb0 + (t + 1) * SLOT);
  }

  // ---- layer 1 x-gates from layer-0 outputs (batched) ----
  gemm_bt<<<dim3(40, 12), 256, 0, stream>>>(hb0 + SLOT, Btx1, xbias + 1536, xg, 1536, 1536, 0);

  // ---- layer 1 recurrence ----
  for (int t = 0; t < TT; ++t) {
    const float* xg_t = xg + (size_t)t * BB * 1536;
    gru_ru<<<8, 256, 0, stream>>>(hb1 + t * SLOT, hs1 + t * SLOT, Btru1, xg_t, ubuf, rh);
    gru_c<<<4, 256, 0, stream>>>(rh, Btc1, xg_t, ubuf,
                                 hs1 + t * SLOT, hs1 + (t + 1) * SLOT, hb1 + (t + 1) * SLOT);
  }

  // ---- logits (batched, permuted to [B,T,V]) ----
  gemm_bt<<<dim3(40, 79), 256, 0, stream>>>(hb1 + SLOT, Wto, bo, out, VV, VV, 1);

  // ---- h_final [L,B,H] ----
  write_hfinal<<<256, 256, 0, stream>>>(hs0 + 40 * SLOT, hs1 + 40 * SLOT, out + (size_t)BB * TT * VV);
}

// Round 3
// 2454.651 us; speedup vs baseline: 3.0806x; 3.0806x over previous
//
#include <hip/hip_runtime.h>
#include <hip/hip_bf16.h>
#include <math.h>

typedef __bf16 bf16_t;
typedef __bf16 bf16x8 __attribute__((ext_vector_type(8)));
typedef float  f32x4 __attribute__((ext_vector_type(4)));
typedef float  f4    __attribute__((ext_vector_type(4)));

#define HS  512
#define BB  128
#define TT  40
#define VV  10000
#define VGGN 4096
#define SLOT ((size_t)65536)   // 128*512
#define NBLK 72

// ============================================================================
// Manual grid barrier (replaces cooperative grid.sync, which failed to launch
// in round 2). Sense via monotonically increasing generation counter.
// __threadfence() at agent scope on gfx950 emits the L2 writeback (release) /
// invalidate (acquire) needed across non-coherent per-XCD L2s (G16, m20).
// Safe: 72 blocks x 64KB LDS -> 2 blocks/CU cap -> all co-resident on 256 CUs.
// ============================================================================
__device__ __forceinline__ void gbar(unsigned* cnt, unsigned* gen, unsigned bar_idx)
{
  __syncthreads();                      // all waves' stores drained to L2
  if (threadIdx.x == 0) {
    __threadfence();                    // release: L2 writeback
    unsigned a = atomicAdd(cnt, 1u);    // device-scope by default (m20)
    if (a == NBLK - 1u) {
      atomicExch(cnt, 0u);
      __threadfence();
      atomicAdd(gen, 1u);               // release barrier bar_idx -> gen = bar_idx+1
    } else {
      while (__hip_atomic_load(gen, __ATOMIC_RELAXED, __HIP_MEMORY_SCOPE_AGENT) <= bar_idx)
        __builtin_amdgcn_s_sleep(2);
      __threadfence();                  // acquire: invalidate stale L1/L2 lines
    }
  }
  __syncthreads();
}

__global__ void zero_sync(unsigned* p) { p[0] = 0u; p[1] = 0u; }

// ============================================================================
// Batched MFMA GEMM: C[M,N] = A[M,512] @ Bt[N,512]^T (+bias), fp32 out.
// ============================================================================
__global__ __launch_bounds__(256) void gemm_bt(
    const bf16_t* __restrict__ A, const bf16_t* __restrict__ Bt,
    const float* __restrict__ bias, float* __restrict__ C,
    int Nvalid, int ldc, int permute_tb)
{
  const int bm = blockIdx.x * 128, bn = blockIdx.y * 128;
  const int tid = threadIdx.x;
  const int wave = tid >> 6, lane = tid & 63;
  const int wm = (wave >> 1) * 64, wn = (wave & 1) * 64;
  const int l15 = lane & 15, kg = lane >> 4;
  const bf16_t* Ap = A + (size_t)(bm + wm + l15) * 512 + kg * 8;
  const bf16_t* Bp = Bt + (size_t)(bn + wn + l15) * 512 + kg * 8;
  f32x4 acc[4][4];
#pragma unroll
  for (int i = 0; i < 4; ++i)
#pragma unroll
    for (int j = 0; j < 4; ++j)
#pragma unroll
      for (int e = 0; e < 4; ++e) acc[i][j][e] = 0.f;

  for (int kk = 0; kk < 512; kk += 32) {
    bf16x8 a[4], b[4];
#pragma unroll
    for (int i = 0; i < 4; ++i) a[i] = *(const bf16x8*)(Ap + (size_t)i * 16 * 512 + kk);
#pragma unroll
    for (int j = 0; j < 4; ++j) b[j] = *(const bf16x8*)(Bp + (size_t)j * 16 * 512 + kk);
#pragma unroll
    for (int i = 0; i < 4; ++i)
#pragma unroll
      for (int j = 0; j < 4; ++j)
        acc[i][j] = __builtin_amdgcn_mfma_f32_16x16x32_bf16(a[i], b[j], acc[i][j], 0, 0, 0);
  }

#pragma unroll
  for (int fm = 0; fm < 4; ++fm) {
#pragma unroll
    for (int fn = 0; fn < 4; ++fn) {
      int n = bn + wn + fn * 16 + l15;
      if (n >= Nvalid) continue;
      float bv = bias ? bias[n] : 0.f;
#pragma unroll
      for (int e = 0; e < 4; ++e) {
        int m = bm + wm + fm * 16 + kg * 4 + e;
        int orow = permute_tb ? ((m & 127) * TT + (m >> 7)) : m;
        C[(size_t)orow * ldc + n] = acc[fm][fn][e] + bv;
      }
    }
  }
}

// ============================================================================
// Persistent GRU recurrence, pipelined across the 2 layers (same structure as
// round 2, cooperative grid.sync replaced by gbar()).
//   blocks [ 0,16): RU layer0  64 rows of Btru0 [1024,512]   K=512
//   blocks [16,48): RU layer1  32 rows of Bt1ru [1024,1024]  K=1024
//   blocks [48,56): C  layer0  64 rows of Btc0  [512,512]    K=512
//   blocks [56,72): C  layer1  32 rows of Btc1  [512,1024]   K=1024
// Stage s (0..40): phase RU {L0 step s | L1 step s-1} ; bar ; phase C ; bar.
// ============================================================================
struct PArgs {
  const bf16_t *Btru0, *Bt1ru, *Btc0, *Btc1;
  const float  *xg0, *bu, *br, *bc;
  bf16_t *hb0_seq, *hb1_seq, *hb1_init, *rh0, *rh1;
  float  *hs0, *hs1, *u0, *u1;
  unsigned *sync;   // [0]=cnt, [1]=gen
};

template<int K>
__device__ __forceinline__ void tile_gemm(
    const bf16_t* __restrict__ A0, const bf16_t* __restrict__ A1,
    const bf16_t* Bs, int wave, int lane, f32x4 (&acc)[2][4])
{
  constexpr int NF = (K == 512) ? 4 : 2;
  const int l15 = lane & 15, kg = lane >> 4;
  const int mw = wave * 32;
#pragma unroll
  for (int i = 0; i < 2; ++i)
#pragma unroll
    for (int f = 0; f < 4; ++f)
#pragma unroll
      for (int e = 0; e < 4; ++e) acc[i][f][e] = 0.f;

#pragma unroll
  for (int kk = 0; kk < K; kk += 32) {
    const bf16_t* Asrc = (kk < 512) ? A0 : A1;
    const int kc = (kk < 512 ? kk : kk - 512) + kg * 8;
    bf16x8 a[2];
#pragma unroll
    for (int i = 0; i < 2; ++i)
      a[i] = *(const bf16x8*)(Asrc + (size_t)(mw + i * 16 + l15) * 512 + kc);
    bf16x8 b[NF];
#pragma unroll
    for (int f = 0; f < NF; ++f) {
      int row = f * 16 + l15;
      int byteoff = row * (2 * K) + ((2 * kk + 16 * kg) ^ ((row & 7) << 4));
      b[f] = *(const bf16x8*)((const char*)Bs + byteoff);
    }
#pragma unroll
    for (int i = 0; i < 2; ++i)
#pragma unroll
      for (int f = 0; f < NF; ++f)
        acc[i][f] = __builtin_amdgcn_mfma_f32_16x16x32_bf16(a[i], b[f], acc[i][f], 0, 0, 0);
  }
}

__global__ __launch_bounds__(256) void gru_persist(PArgs P)
{
  const int bid = blockIdx.x, tid = threadIdx.x;
  const int wave = tid >> 6, lane = tid & 63;
  const int l15 = lane & 15, kg = lane >> 4;
  const int mw = wave * 32;
  unsigned* cnt = P.sync;
  unsigned* gen = P.sync + 1;

  int role, q;
  if (bid < 16)      { role = 0; q = bid; }
  else if (bid < 48) { role = 1; q = bid - 16; }
  else if (bid < 56) { role = 2; q = bid - 48; }
  else               { role = 3; q = bid - 56; }
  const int K  = (role == 0 || role == 2) ? 512 : 1024;
  const int NT = (K == 512) ? 64 : 32;
  const int tileBase = q * NT;

  const bf16_t* Wsrc =
      role == 0 ? P.Btru0 + (size_t)tileBase * 512 :
      role == 1 ? P.Bt1ru + (size_t)tileBase * 1024 :
      role == 2 ? P.Btc0  + (size_t)tileBase * 512 :
                  P.Btc1  + (size_t)tileBase * 1024;

  // ---- stage weight tile into LDS once, swizzled ----
  __shared__ bf16_t Bs[32768];   // 64 KB
  {
    const int rsh = (K == 512) ? 10 : 11;
    const int rmask = 2 * K - 1;
#pragma unroll
    for (int it = 0; it < 16; ++it) {
      int ofs = (it * 256 + tid) * 16;
      int row = ofs >> rsh, cb = ofs & rmask;
      *(f4*)((char*)Bs + row * 2 * K + (cb ^ ((row & 7) << 4))) =
          *(const f4*)((const char*)Wsrc + ofs);
    }
  }
  __syncthreads();

  for (int s = 0; s <= 40; ++s) {
    // ---------------- phase RU ----------------
    if (role == 0 && s < 40) {
      f32x4 acc[2][4];
      const bf16_t* A0 = P.hb0_seq + (size_t)s * SLOT;
      tile_gemm<512>(A0, A0, Bs, wave, lane, acc);
      const float* xg = P.xg0 + (size_t)s * 128 * 1536;
#pragma unroll
      for (int i = 0; i < 2; ++i)
#pragma unroll
        for (int f = 0; f < 4; ++f)
#pragma unroll
          for (int e = 0; e < 4; ++e) {
            int m = mw + i * 16 + kg * 4 + e;
            int np = tileBase + f * 16 + l15;
            float pre = acc[i][f][e] + xg[(size_t)m * 1536 + np];
            float sg = 1.f / (1.f + expf(-pre));
            if (np < 512) P.u0[m * 512 + np] = sg;
            else {
              int n = np - 512;
              P.rh0[m * 512 + n] = (bf16_t)(sg * P.hs0[m * 512 + n]);
            }
          }
    } else if (role == 1 && s >= 1) {
      f32x4 acc[2][4];
      const bf16_t* Ax = P.hb0_seq + (size_t)s * SLOT;
      const bf16_t* Ah = (s == 1) ? P.hb1_init : P.hb1_seq + (size_t)(s - 2) * SLOT;
      tile_gemm<1024>(Ax, Ah, Bs, wave, lane, acc);
#pragma unroll
      for (int i = 0; i < 2; ++i)
#pragma unroll
        for (int f = 0; f < 2; ++f)
#pragma unroll
          for (int e = 0; e < 4; ++e) {
            int m = mw + i * 16 + kg * 4 + e;
            int np = tileBase + f * 16 + l15;
            float bias = (np < 512) ? P.bu[512 + np] : P.br[np];
            float pre = acc[i][f][e] + bias;
            float sg = 1.f / (1.f + expf(-pre));
            if (np < 512) P.u1[m * 512 + np] = sg;
            else {
              int n = np - 512;
              P.rh1[m * 512 + n] = (bf16_t)(sg * P.hs1[m * 512 + n]);
            }
          }
    }
    gbar(cnt, gen, 2 * s);
    // ---------------- phase C ----------------
    if (role == 2 && s < 40) {
      f32x4 acc[2][4];
      tile_gemm<512>(P.rh0, P.rh0, Bs, wave, lane, acc);
      const float* xg = P.xg0 + (size_t)s * 128 * 1536;
#pragma unroll
      for (int i = 0; i < 2; ++i)
#pragma unroll
        for (int f = 0; f < 4; ++f)
#pragma unroll
          for (int e = 0; e < 4; ++e) {
            int m = mw + i * 16 + kg * 4 + e;
            int n = tileBase + f * 16 + l15;
            float c = tanhf(acc[i][f][e] + xg[(size_t)m * 1536 + 1024 + n]);
            float u = P.u0[m * 512 + n];
            float h = P.hs0[m * 512 + n];
            float hn = u * h + (1.f - u) * c;
            P.hs0[m * 512 + n] = hn;
            P.hb0_seq[(size_t)(s + 1) * SLOT + m * 512 + n] = (bf16_t)hn;
          }
    } else if (role == 3 && s >= 1) {
      f32x4 acc[2][4];
      tile_gemm<1024>(P.hb0_seq + (size_t)s * SLOT, P.rh1, Bs, wave, lane, acc);
#pragma unroll
      for (int i = 0; i < 2; ++i)
#pragma unroll
        for (int f = 0; f < 2; ++f)
#pragma unroll
          for (int e = 0; e < 4; ++e) {
            int m = mw + i * 16 + kg * 4 + e;
            int n = tileBase + f * 16 + l15;
            float c = tanhf(acc[i][f][e] + P.bc[512 + n]);
            float u = P.u1[m * 512 + n];
            float h = P.hs1[m * 512 + n];
            float hn = u * h + (1.f - u) * c;
            P.hs1[m * 512 + n] = hn;
            P.hb1_seq[(size_t)(s - 1) * SLOT + m * 512 + n] = (bf16_t)hn;
          }
    }
    gbar(cnt, gen, 2 * s + 1);
  }
}

// ============================================================================
// h0 = tanh(vgg @ W_in + b_in) via bf16 MFMA, split-K=8.
// ============================================================================
__global__ __launch_bounds__(256) void h0_gemm(
    const bf16_t* __restrict__ vggb, const bf16_t* __restrict__ Wint,
    float* __restrict__ part)
{
  const int bn = blockIdx.x * 128, z = blockIdx.y, k0 = z * 512;
  const int tid = threadIdx.x;
  const int wave = tid >> 6, lane = tid & 63;
  const int wm = (wave >> 1) * 64, wn = (wave & 1) * 64;
  const int l15 = lane & 15, kg = lane >> 4;
  const bf16_t* Ap = vggb + (size_t)(wm + l15) * 4096 + k0 + kg * 8;
  const bf16_t* Bp = Wint + (size_t)(bn + wn + l15) * 4096 + k0 + kg * 8;
  f32x4 acc[4][4];
#pragma unroll
  for (int i = 0; i < 4; ++i)
#pragma unroll
    for (int j = 0; j < 4; ++j)
#pragma unroll
      for (int e = 0; e < 4; ++e) acc[i][j][e] = 0.f;
  for (int kk = 0; kk < 512; kk += 32) {
    bf16x8 a[4], b[4];
#pragma unroll
    for (int i = 0; i < 4; ++i) a[i] = *(const bf16x8*)(Ap + (size_t)i * 16 * 4096 + kk);
#pragma unroll
    for (int j = 0; j < 4; ++j) b[j] = *(const bf16x8*)(Bp + (size_t)j * 16 * 4096 + kk);
#pragma unroll
    for (int i = 0; i < 4; ++i)
#pragma unroll
      for (int j = 0; j < 4; ++j)
        acc[i][j] = __builtin_amdgcn_mfma_f32_16x16x32_bf16(a[i], b[j], acc[i][j], 0, 0, 0);
  }
#pragma unroll
  for (int fm = 0; fm < 4; ++fm)
#pragma unroll
    for (int fn = 0; fn < 4; ++fn) {
      int n = bn + wn + fn * 16 + l15;
#pragma unroll
      for (int e = 0; e < 4; ++e) {
        int m = wm + fm * 16 + kg * 4 + e;
        part[(size_t)z * SLOT + m * 512 + n] = acc[fm][fn][e];
      }
    }
}

__global__ void h0_fin(const float* __restrict__ part, const float* __restrict__ bin,
                       float* __restrict__ hs0, float* __restrict__ hs1,
                       bf16_t* __restrict__ hb00, bf16_t* __restrict__ hb1i)
{
  int i = blockIdx.x * 256 + threadIdx.x;   // 65536
  int n = i & 511;
  float s = bin[n];
#pragma unroll
  for (int z = 0; z < 8; ++z) s += part[(size_t)z * SLOT + i];
  float v = tanhf(s);
  hs0[i] = v; hs1[i] = v;
  hb00[i] = (bf16_t)v; hb1i[i] = (bf16_t)v;
}

__global__ void conv_bf16(const float* __restrict__ src, bf16_t* __restrict__ dst)
{
  int i = blockIdx.x * 256 + threadIdx.x;   // * 4 elems
  f4 v = ((const f4*)src)[i];
  dst[i * 4 + 0] = (bf16_t)v[0]; dst[i * 4 + 1] = (bf16_t)v[1];
  dst[i * 4 + 2] = (bf16_t)v[2]; dst[i * 4 + 3] = (bf16_t)v[3];
}

// Embedding gather -> bf16 A matrix, row m = t*128+b.
__global__ void gather_emb(const int* __restrict__ tok, const float* __restrict__ emb,
                           bf16_t* __restrict__ A)
{
  int m = blockIdx.x;
  int t = m >> 7, b = m & 127;
  int tk = tok[b * TT + t];
  const float* src = emb + (size_t)tk * 512;
  int i = threadIdx.x;
  f4 v = *(const f4*)(src + i * 4);
  bf16_t* dst = A + (size_t)m * 512 + i * 4;
  dst[0] = (bf16_t)v[0]; dst[1] = (bf16_t)v[1];
  dst[2] = (bf16_t)v[2]; dst[3] = (bf16_t)v[3];
}

// Generic transposes: dst[n*dstld + k] = src[k*512 + n]  (bf16 out)
struct TJob { const float* src; bf16_t* dst; int K; int dstld; };
struct TJobs10 { TJob j[10]; };
__global__ void transpose_gen(TJobs10 jobs)
{
  TJob jb = jobs.j[blockIdx.z];
  int k0 = blockIdx.x * 32;
  if (k0 >= jb.K) return;
  int n0 = blockIdx.y * 32;
  __shared__ float tile[32][33];
  int tx = threadIdx.x, ty = threadIdx.y;
#pragma unroll
  for (int r = 0; r < 4; ++r)
    tile[ty + 8 * r][tx] = jb.src[(size_t)(k0 + ty + 8 * r) * 512 + n0 + tx];
  __syncthreads();
#pragma unroll
  for (int r = 0; r < 4; ++r)
    jb.dst[(size_t)(n0 + ty + 8 * r) * jb.dstld + k0 + tx] = (bf16_t)tile[tx][ty + 8 * r];
}

// W_out [512,10000] -> Wto [10112,512] bf16, zero-padded rows >= 10000.
__global__ void transpose_wout(const float* __restrict__ W, bf16_t* __restrict__ dst)
{
  __shared__ float tile[32][33];
  int k0 = blockIdx.x * 32, n0 = blockIdx.y * 32;
  int tx = threadIdx.x, ty = threadIdx.y;
#pragma unroll
  for (int r = 0; r < 4; ++r) {
    int n = n0 + tx;
    tile[ty + 8 * r][tx] = (n < VV) ? W[(size_t)(k0 + ty + 8 * r) * VV + n] : 0.f;
  }
  __syncthreads();
#pragma unroll
  for (int r = 0; r < 4; ++r)
    dst[(size_t)(n0 + ty + 8 * r) * 512 + k0 + tx] = (bf16_t)tile[tx][ty + 8 * r];
}

// xbias[j][1536] = concat(b_u[j], b_r[j], b_c[j])  (only j=0 used)
__global__ void build_xbias(const float* __restrict__ bu, const float* __restrict__ br,
                            const float* __restrict__ bc, float* __restrict__ xb)
{
  int i = blockIdx.x * 256 + threadIdx.x;
  if (i < 2 * 1536) {
    int j = i / 1536, qq = i % 1536;
    int g = qq >> 9, n = qq & 511;
    const float* src = (g == 0) ? bu : (g == 1) ? br : bc;
    xb[i] = src[j * 512 + n];
  }
}

__global__ void write_hfinal(const float* __restrict__ hs0_last,
                             const float* __restrict__ hs1_last,
                             float* __restrict__ out)
{
  int i = blockIdx.x * 256 + threadIdx.x;
  out[i] = hs0_last[i];
  out[65536 + i] = hs1_last[i];
}

// ============================================================================
extern "C" void kernel_launch(void* const* d_in, const int* in_sizes, int n_in,
                              void* d_out, int out_size, void* d_ws, size_t ws_size,
                              hipStream_t stream)
{
  const int*   tok = (const int*)  d_in[0];
  const float* vgg = (const float*)d_in[1];
  const float* emb = (const float*)d_in[2];
  const float* Win = (const float*)d_in[3];
  const float* bin = (const float*)d_in[4];
  const float* Wu  = (const float*)d_in[5];
  const float* bu  = (const float*)d_in[6];
  const float* Wr  = (const float*)d_in[7];
  const float* br  = (const float*)d_in[8];
  const float* Wc  = (const float*)d_in[9];
  const float* bc  = (const float*)d_in[10];
  const float* Wo  = (const float*)d_in[11];
  const float* bo  = (const float*)d_in[12];
  float* out = (float*)d_out;

  size_t off = 0;
  auto alloc = [&](size_t bytes) -> void* {
    void* p = (char*)d_ws + off;
    off += (bytes + 255) & ~(size_t)255;
    return p;
  };
  float*  hs0   = (float*) alloc(SLOT * 4);
  float*  hs1   = (float*) alloc(SLOT * 4);
  float*  u0    = (float*) alloc(SLOT * 4);
  float*  u1    = (float*) alloc(SLOT * 4);
  bf16_t* rh0   = (bf16_t*)alloc(SLOT * 2);
  bf16_t* rh1   = (bf16_t*)alloc(SLOT * 2);
  bf16_t* hb0_seq = (bf16_t*)alloc(41 * SLOT * 2);
  bf16_t* hb1_seq = (bf16_t*)alloc(40 * SLOT * 2);
  bf16_t* hb1_init= (bf16_t*)alloc(SLOT * 2);
  bf16_t* Aemb  = (bf16_t*)alloc((size_t)TT * BB * 512 * 2);
  float*  xg0   = (float*) alloc((size_t)TT * BB * 1536 * 4);
  bf16_t* Btx0  = (bf16_t*)alloc((size_t)1536 * 512 * 2);
  bf16_t* Btru0 = (bf16_t*)alloc((size_t)1024 * 512 * 2);
  bf16_t* Btc0  = (bf16_t*)alloc((size_t)512 * 512 * 2);
  bf16_t* Bt1ru = (bf16_t*)alloc((size_t)1024 * 1024 * 2);
  bf16_t* Btc1  = (bf16_t*)alloc((size_t)512 * 1024 * 2);
  bf16_t* Wto   = (bf16_t*)alloc((size_t)10112 * 512 * 2);
  bf16_t* Wint  = (bf16_t*)alloc((size_t)512 * 4096 * 2);
  bf16_t* vggb  = (bf16_t*)alloc((size_t)128 * 4096 * 2);
  float*  h0part= (float*) alloc(8 * SLOT * 4);
  float*  xbias = (float*) alloc(2 * 1536 * 4);
  unsigned* syncws = (unsigned*) alloc(256);
  if (off > ws_size) return;

  // ---- prep: transposes / converts ----
  TJobs10 tj;
  tj.j[0] = { Wu,                Btx0,                512, 512 };
  tj.j[1] = { Wr,                Btx0 + 262144,       512, 512 };
  tj.j[2] = { Wc,                Btx0 + 524288,       512, 512 };
  tj.j[3] = { Wu + 262144,       Btru0,               512, 512 };
  tj.j[4] = { Wr + 262144,       Btru0 + 262144,      512, 512 };
  tj.j[5] = { Wc + 262144,       Btc0,                512, 512 };
  tj.j[6] = { Wu + 524288,       Bt1ru,               1024, 1024 };
  tj.j[7] = { Wr + 524288,       Bt1ru + 524288,      1024, 1024 };
  tj.j[8] = { Wc + 524288,       Btc1,                1024, 1024 };
  tj.j[9] = { Win,               Wint,                4096, 4096 };
  transpose_gen<<<dim3(128, 16, 10), dim3(32, 8), 0, stream>>>(tj);
  transpose_wout<<<dim3(16, 316), dim3(32, 8), 0, stream>>>(Wo, Wto);
  build_xbias<<<12, 256, 0, stream>>>(bu, br, bc, xbias);
  gather_emb<<<TT * BB, 128, 0, stream>>>(tok, emb, Aemb);
  conv_bf16<<<512, 256, 0, stream>>>(vgg, vggb);
  zero_sync<<<1, 1, 0, stream>>>(syncws);

  // ---- h0 init (bf16 MFMA, split-K) ----
  h0_gemm<<<dim3(4, 8), 256, 0, stream>>>(vggb, Wint, h0part);
  h0_fin<<<256, 256, 0, stream>>>(h0part, bin, hs0, hs1, hb0_seq, hb1_init);

  // ---- layer-0 x-gates (batched) ----
  gemm_bt<<<dim3(40, 12), 256, 0, stream>>>(Aemb, Btx0, xbias, xg0, 1536, 1536, 0);

  // ---- persistent pipelined recurrence (plain launch + manual grid barrier) ----
  PArgs pa;
  pa.Btru0 = Btru0; pa.Bt1ru = Bt1ru; pa.Btc0 = Btc0; pa.Btc1 = Btc1;
  pa.xg0 = xg0; pa.bu = bu; pa.br = br; pa.bc = bc;
  pa.hb0_seq = hb0_seq; pa.hb1_seq = hb1_seq; pa.hb1_init = hb1_init;
  pa.rh0 = rh0; pa.rh1 = rh1;
  pa.hs0 = hs0; pa.hs1 = hs1; pa.u0 = u0; pa.u1 = u1;
  pa.sync = syncws;
  gru_persist<<<NBLK, 256, 0, stream>>>(pa);

  // ---- logits (batched, permuted to [B,T,V]) ----
  gemm_bt<<<dim3(40, 79), 256, 0, stream>>>(hb1_seq, Wto, bo, out, VV, VV, 1);

  // ---- h_final [L,B,H] ----
  write_hfinal<<<256, 256, 0, stream>>>(hs0, hs1, out + (size_t)BB * TT * VV);
}